// Round 5
// baseline (167.137 us; speedup 1.0000x reference)
//
#include <hip/hip_runtime.h>

typedef __bf16 bf16;
typedef __bf16 bf16x8 __attribute__((ext_vector_type(8)));
typedef float f32x4 __attribute__((ext_vector_type(4)));
typedef float f32x16 __attribute__((ext_vector_type(16)));

#define MFMA16(a, b, c) __builtin_amdgcn_mfma_f32_16x16x32_bf16(a, b, c, 0, 0, 0)
#define MFMA32(a, b, c) __builtin_amdgcn_mfma_f32_32x32x16_bf16(a, b, c, 0, 0, 0)

// scale (1/sqrt(64)) * log2(e), folded into q at the QKV epilogue.
#define QSCALE 0.1803368801111137f

static __device__ __forceinline__ unsigned int pack2(float a, float b) {
  unsigned short s0 = __builtin_bit_cast(unsigned short, (bf16)a);
  unsigned short s1 = __builtin_bit_cast(unsigned short, (bf16)b);
  return (unsigned int)s0 | ((unsigned int)s1 << 16);
}

// async global->LDS, 16B per lane. LDS dest is wave-uniform base + lane*16.
static __device__ __forceinline__ void gl16(const bf16* g, bf16* l) {
  __builtin_amdgcn_global_load_lds(
      (const __attribute__((address_space(1))) unsigned int*)g,
      (__attribute__((address_space(3))) unsigned int*)l, 16, 0, 0);
}

// ---------------------------------------------------------------------------
// Fused preprocessing: blocks [0,1024) convert qkv_w/proj_w fp32->bf16;
// blocks [1024,1536) LayerNorm x (B=8,C=512,HW=1024) fp32 -> xn (B*HW,C) bf16.
// ---------------------------------------------------------------------------
__global__ __launch_bounds__(256) void prep_kernel(
    const float* __restrict__ qkvw, const float* __restrict__ projw,
    bf16* __restrict__ wc, const float* __restrict__ x,
    const float* __restrict__ lnw, const float* __restrict__ lnb,
    bf16* __restrict__ xn) {
  __shared__ float tile[512 * 17];  // 34816 B (ln path only)
  __shared__ float wsh[512];
  __shared__ float bsh[512];
  const int t = threadIdx.x;
  if (blockIdx.x < 1024) {
    // ---- weight convert path ----
    int c4 = blockIdx.x * 256 + t;  // 0..262143
    const float* src = (c4 < 196608) ? (qkvw + (size_t)c4 * 4)
                                     : (projw + (size_t)(c4 - 196608) * 4);
    float4 v = *(const float4*)src;
    uint2 o;
    o.x = pack2(v.x, v.y);
    o.y = pack2(v.z, v.w);
    *(uint2*)&wc[(size_t)c4 * 4] = o;
    return;
  }
  // ---- layernorm path ----
  const int bid = blockIdx.x - 1024;
  const int b = bid >> 6;          // 8 batches
  const int p0 = (bid & 63) * 16;  // 64 pixel groups of 16
  for (int i = t; i < 512; i += 256) {
    wsh[i] = lnw[i];
    bsh[i] = lnb[i];
  }
  const float* xb = x + (size_t)b * 524288 + p0;
#pragma unroll
  for (int i = 0; i < 8; ++i) {
    int chunk = t + 256 * i;  // 2048 float4 chunks = 512 rows x 4
    int c = chunk >> 2, px4 = (chunk & 3) * 4;
    float4 v = *(const float4*)&xb[(size_t)c * 1024 + px4];
    tile[c * 17 + px4 + 0] = v.x;
    tile[c * 17 + px4 + 1] = v.y;
    tile[c * 17 + px4 + 2] = v.z;
    tile[c * 17 + px4 + 3] = v.w;
  }
  __syncthreads();
  const int pix = t >> 4, j = t & 15;  // 16 threads per pixel
  float sum = 0.f, sq = 0.f;
#pragma unroll
  for (int i = 0; i < 32; ++i) {
    int c = i * 16 + j;
    float v = tile[c * 17 + pix];
    sum += v;
    sq += v * v;
  }
#pragma unroll
  for (int m = 1; m <= 8; m <<= 1) {
    sum += __shfl_xor(sum, m);
    sq += __shfl_xor(sq, m);
  }
  float mu = sum * (1.f / 512.f);
  float var = sq * (1.f / 512.f) - mu * mu;
  float rstd = rsqrtf(var + 1e-5f);
  unsigned int* orow =
      (unsigned int*)(xn + ((size_t)(b * 1024 + p0 + pix)) * 512);
#pragma unroll
  for (int i = 0; i < 16; ++i) {
    int dw = i * 16 + j;  // dword index 0..255
    int c0 = 2 * dw, c1 = 2 * dw + 1;
    float v0 = (tile[c0 * 17 + pix] - mu) * rstd * wsh[c0] + bsh[c0];
    float v1 = (tile[c1 * 17 + pix] - mu) * rstd * wsh[c1] + bsh[c1];
    orow[dw] = pack2(v0, v1);
  }
}

// ---------------------------------------------------------------------------
// QKV GEMM: C = A * B^T, A=xn (8192x512), B=qkv_w (1536x512). Tile 128x128,
// BK=32, double-buffered global_load_lds staging, one barrier/iter.
// LDS granule swizzle (both-sides-or-neither): chunk (r, g) stores the
// global granule g ^ f(r), f(r) = (r>>1)&3, via pre-swizzled SOURCE address;
// fragment reads fetch slot (quad ^ f(row)).
// Epilogue: +bias, q pre-scaled by QSCALE; q/k scattered (b,h,p,d); V blocks
// transposed through LDS then stored as coalesced 128B vT rows (b,h,d,p).
// vT COLUMN ORDER IS PERMUTED: within each 16-pixel group, p-bit2 and p-bit3
// are swapped (stored order {0-3,8-11,4-7,12-15}). This makes the attention
// PV B-fragment (k = (lane>>5)*8+j of mfma_32x32x16) line up with the
// Sᵀ C-layout (row=(reg&3)+8*(reg>>2)+4*(lane>>5)) with no cross-lane moves.
// ---------------------------------------------------------------------------
__global__ __launch_bounds__(256, 3) void gemm_qkv(
    const bf16* __restrict__ A, const bf16* __restrict__ Bm,
    const float* __restrict__ bias, bf16* __restrict__ oq,
    bf16* __restrict__ okk, bf16* __restrict__ ov) {
  // layout: A buf0 [0,4096), A buf1 [4096,8192), B buf0 [8192,12288),
  // B buf1 [12288,16384). Reused whole as V-transpose scratch in epilogue.
  __shared__ bf16 smem[16384];  // 32KB
  const int t = threadIdx.x;
  const int lane = t & 63, w = t >> 6;
  const int quad = lane >> 4, r16 = lane & 15;
  const int wm = w >> 1, wn = w & 1;
  // panel swizzle: 8 m-tiles x 12 n-tiles per panel
  const int pid = blockIdx.x;
  const int panel = pid / 96, within = pid % 96;
  const int m0 = (panel * 8 + (within & 7)) * 128;
  const int n0 = (within >> 3) * 128;
  // staging: per k-tile each matrix is 512 chunks of 8 elems (128 rows x 4
  // granules); wave w issues j=0,1 for A and for B: chunk c=(w*2+j)*64+lane.
  int sr[2], sc[2];
#pragma unroll
  for (int j = 0; j < 2; ++j) {
    int c = (w * 2 + j) * 64 + lane;
    int r = c >> 2, g = c & 3;
    sr[j] = r;                          // row 0..127
    sc[j] = (g ^ ((r >> 1) & 3)) * 8;   // pre-swizzled source granule
  }
  const int gx = (r16 >> 1) & 3;  // lane-uniform read-side granule xor
  f32x4 acc[4][4] = {};
  // prologue: stage k-tile 0 into buffer 0
#pragma unroll
  for (int j = 0; j < 2; ++j) {
    gl16(&A[(size_t)(m0 + sr[j]) * 512 + sc[j]], &smem[(w * 2 + j) * 512]);
    gl16(&Bm[(size_t)(n0 + sr[j]) * 512 + sc[j]],
         &smem[8192 + (w * 2 + j) * 512]);
  }
  __syncthreads();
  for (int it = 0; it < 16; ++it) {
    const int cur = it & 1, nxt = cur ^ 1;
    if (it < 15) {
      int k1 = (it + 1) * 32;
#pragma unroll
      for (int j = 0; j < 2; ++j) {
        gl16(&A[(size_t)(m0 + sr[j]) * 512 + k1 + sc[j]],
             &smem[nxt * 4096 + (w * 2 + j) * 512]);
        gl16(&Bm[(size_t)(n0 + sr[j]) * 512 + k1 + sc[j]],
             &smem[8192 + nxt * 4096 + (w * 2 + j) * 512]);
      }
    }
    const bf16* ac = &smem[cur * 4096];
    const bf16* bc = &smem[8192 + cur * 4096];
    bf16x8 af[4], bfr[4];
#pragma unroll
    for (int i = 0; i < 4; ++i) {
      int row = wm * 64 + i * 16 + r16;
      af[i] = *(const bf16x8*)&ac[row * 32 + (quad ^ gx) * 8];
    }
#pragma unroll
    for (int i = 0; i < 4; ++i) {
      int row = wn * 64 + i * 16 + r16;
      bfr[i] = *(const bf16x8*)&bc[row * 32 + (quad ^ gx) * 8];
    }
#pragma unroll
    for (int tm = 0; tm < 4; ++tm)
#pragma unroll
      for (int tn = 0; tn < 4; ++tn)
        acc[tm][tn] = MFMA16(af[tm], bfr[tn], acc[tm][tn]);
    __syncthreads();
  }
  if (n0 < 1024) {
    // q / k blocks: direct scatter (d-contiguous 32B segments)
#pragma unroll
    for (int tm = 0; tm < 4; ++tm) {
#pragma unroll
      for (int tn = 0; tn < 4; ++tn) {
        int n = n0 + wn * 64 + tn * 16 + r16;
        float bn = bias[n];
        int comp = n >> 9, h = (n >> 6) & 7, d = n & 63;
#pragma unroll
        for (int r = 0; r < 4; ++r) {
          int m = m0 + wm * 64 + tm * 16 + quad * 4 + r;
          float v = acc[tm][tn][r] + bn;
          int b = m >> 10, p = m & 1023;
          size_t base = ((size_t)(b * 8 + h)) * 65536;
          if (comp == 0)
            oq[base + (size_t)p * 64 + d] = (bf16)(v * QSCALE);
          else
            okk[base + (size_t)p * 64 + d] = (bf16)v;
        }
      }
    }
  } else {
    // V block: per-wave LDS transpose (64d x 64p, stride 64, xor-swizzled at
    // 8-elem granules) then coalesced 128B-row stores of vT (b,h,d,p).
    // Column permutation (p bit2<->bit3 within each 16) baked in here:
    // original p_local = tm*16 + quad*4 + r  ->  stored at
    // tm*16 + swapbits(quad)*4 + r, i.e. granule tm*2+(quad&1), off (quad>>1)*4.
    bf16* tb = &smem[w * 4096];
#pragma unroll
    for (int tn = 0; tn < 4; ++tn) {
      int n = n0 + wn * 64 + tn * 16 + r16;
      float bn = bias[n];
      int row = tn * 16 + r16;  // d_local
#pragma unroll
      for (int tm = 0; tm < 4; ++tm) {
        f32x4 a = acc[tm][tn];
        uint2 pk;
        pk.x = pack2(a[0] + bn, a[1] + bn);
        pk.y = pack2(a[2] + bn, a[3] + bn);
        int g = (tm * 2 + (quad & 1)) ^ (row & 7);
        *(uint2*)&tb[row * 64 + g * 8 + (quad >> 1) * 4] = pk;
      }
    }
    // wave-private region: no barrier needed (lgkmcnt orders write->read)
    const int h = ((n0 - 1024) >> 6) + wn;
    const int mw = m0 + wm * 64;
    const int b = mw >> 10;
    bf16* vbase = ov + ((size_t)(b * 8 + h)) * 65536 + (mw & 1023);
#pragma unroll
    for (int pass = 0; pass < 8; ++pass) {
      int row = pass * 8 + (lane >> 3);
      int g = (lane & 7) ^ (row & 7);
      uint4 vd = *(uint4*)&tb[row * 64 + g * 8];
      *(uint4*)&vbase[(size_t)row * 1024 + (lane & 7) * 8] = vd;
    }
  }
}

// ---------------------------------------------------------------------------
// Proj GEMM: C = W * A^T, W=proj_w (512x512), A=attn out (8192x512).
// Tile 64x64 (grid 8x128 = 1024 blocks), BK=64, double-buffered swizzled
// global_load_lds staging. Epilogue: +bias[m] +residual, fp32 out (B,C,HW).
// ---------------------------------------------------------------------------
__global__ __launch_bounds__(256, 4) void gemm_proj(
    const bf16* __restrict__ Wm, const bf16* __restrict__ A,
    const float* __restrict__ bias, const float* __restrict__ resid,
    float* __restrict__ op) {
  __shared__ bf16 ash[2][64 * 64];
  __shared__ bf16 bsh[2][64 * 64];
  const int t = threadIdx.x;
  const int lane = t & 63, w = t >> 6;
  const int quad = lane >> 4, r16 = lane & 15;
  const int wm = w >> 1, wn = w & 1;
  const int m0 = blockIdx.x * 64, n0 = blockIdx.y * 64;
  int soff[2], sr[2];
#pragma unroll
  for (int j = 0; j < 2; ++j) {
    int c = (w * 2 + j) * 64 + lane;
    int r = c >> 3, cc = c & 7;
    sr[j] = r;
    soff[j] = (cc ^ (r & 7)) * 8;
  }
  f32x4 acc[2][2] = {};
  // prologue: stage k-tile 0 into buffer 0
#pragma unroll
  for (int j = 0; j < 2; ++j) {
    gl16(&Wm[(size_t)(m0 + sr[j]) * 512 + soff[j]], &ash[0][(w * 2 + j) * 512]);
    gl16(&A[(size_t)(n0 + sr[j]) * 512 + soff[j]], &bsh[0][(w * 2 + j) * 512]);
  }
  __syncthreads();
  for (int it = 0; it < 8; ++it) {
    const int cur = it & 1, nxt = cur ^ 1;
    if (it < 7) {
      int k1 = (it + 1) * 64;
#pragma unroll
      for (int j = 0; j < 2; ++j) {
        gl16(&Wm[(size_t)(m0 + sr[j]) * 512 + k1 + soff[j]],
             &ash[nxt][(w * 2 + j) * 512]);
        gl16(&A[(size_t)(n0 + sr[j]) * 512 + k1 + soff[j]],
             &bsh[nxt][(w * 2 + j) * 512]);
      }
    }
#pragma unroll
    for (int kc = 0; kc < 2; ++kc) {
      bf16x8 af[2], bfr[2];
#pragma unroll
      for (int i = 0; i < 2; ++i) {
        int row = wm * 32 + i * 16 + r16;
        af[i] = *(const bf16x8*)&ash[cur][row * 64 +
                                          ((kc * 4 + quad) ^ (r16 & 7)) * 8];
      }
#pragma unroll
      for (int i = 0; i < 2; ++i) {
        int row = wn * 32 + i * 16 + r16;
        bfr[i] = *(const bf16x8*)&bsh[cur][row * 64 +
                                           ((kc * 4 + quad) ^ (r16 & 7)) * 8];
      }
#pragma unroll
      for (int tm = 0; tm < 2; ++tm)
#pragma unroll
        for (int tn = 0; tn < 2; ++tn)
          acc[tm][tn] = MFMA16(af[tm], bfr[tn], acc[tm][tn]);
    }
    __syncthreads();
  }
#pragma unroll
  for (int tm = 0; tm < 2; ++tm) {
#pragma unroll
    for (int tn = 0; tn < 2; ++tn) {
      int n = n0 + wn * 32 + tn * 16 + r16;
      int b = n >> 10, p = n & 1023;
#pragma unroll
      for (int r = 0; r < 4; ++r) {
        int m = m0 + wm * 32 + tm * 16 + quad * 4 + r;
        size_t idx = ((size_t)(b * 512 + m)) * 1024 + p;
        op[idx] = acc[tm][tn][r] + bias[m] + resid[idx];
      }
    }
  }
}

// ---------------------------------------------------------------------------
// Flash attention, 32x32x16-MFMA, 64 q-rows per wave. Swapped QK^T:
// S^T = mfma(K, Q) puts q = lane&31; each lane owns a full 32-kv slice of one
// P row, softmax entirely in-register. TWO q-subtiles per wave share every
// K-fragment and V-fragment LDS read: per wave-iter 16 ds_read_b128 feed
// 32 MFMA32s (LDS demand per unit work halved vs 32q/wave; MFMA pipe is now
// the binding resource at ~1024 cyc/iter/CU).
// Geometry: 4 waves x 64q = 256 q/block; grid (64 bh, 4 qt) = 256 blocks =
// 1 block/CU; id%8 = bh%8 keeps one bh's K/V on one XCD L2.
// ---------------------------------------------------------------------------
__global__ __launch_bounds__(256, 1) void attn_kernel(
    const bf16* __restrict__ q, const bf16* __restrict__ k,
    const bf16* __restrict__ vT, bf16* __restrict__ o) {
  __shared__ bf16 kt[2][64 * 64];  // 2x8KB K tiles (kv-row major, swizzled)
  __shared__ bf16 vt[2][64 * 64];  // 2x8KB vT tiles (d-row major, swizzled)
  const int t = threadIdx.x;
  const int lane = t & 63, w = t >> 6;
  const int l31 = lane & 31, hi = lane >> 5;
  const int bh = blockIdx.x;
  const int qt0 = blockIdx.y * 256;
  const bf16* qb = q + (size_t)bh * 65536;
  const bf16* kb = k + (size_t)bh * 65536;
  const bf16* vb = vT + (size_t)bh * 65536;
  // Q as B-fragment: col = q = lane&31, k(=d) = ks*16 + hi*8 + j.
  // Two q-subtiles per wave: rows w*64+l31 (a) and w*64+32+l31 (b).
  const int qra = qt0 + w * 64 + l31;
  bf16x8 qfa[4], qfb[4];
#pragma unroll
  for (int ks = 0; ks < 4; ++ks) {
    qfa[ks] = *(const bf16x8*)&qb[(size_t)qra * 64 + ks * 16 + hi * 8];
    qfb[ks] = *(const bf16x8*)&qb[(size_t)(qra + 32) * 64 + ks * 16 + hi * 8];
  }
  // staging: 512 chunks/tile; wave w issues j=0,1; chunk c=(w*2+j)*64+lane
  int offk[2], offv[2];
#pragma unroll
  for (int j = 0; j < 2; ++j) {
    int c = (w * 2 + j) * 64 + lane;
    int r = c >> 3, cc = c & 7;
    int sw = (cc ^ (r & 7)) * 8;
    offk[j] = r * 64 + sw;    // K: row=kv (stride 64)
    offv[j] = r * 1024 + sw;  // vT: row=d (stride 1024)
  }
  f32x16 oacca[2] = {};  // O_a[q=(reg&3)+8*(reg>>2)+4*hi][d=mf*32+l31]
  f32x16 oaccb[2] = {};
  float rsa = 0.f, rsb = 0.f;  // exp row-sum partials (this hi-half's kv)
  const int swz = l31 & 7;
  // prologue: stage tile 0
#pragma unroll
  for (int j = 0; j < 2; ++j) {
    gl16(&kb[offk[j]], &kt[0][(w * 2 + j) * 512]);
    gl16(&vb[offv[j]], &vt[0][(w * 2 + j) * 512]);
  }
  __syncthreads();
  for (int it = 0; it < 16; ++it) {
    const int cur = it & 1, nxt = cur ^ 1;
    if (it < 15) {
      int kv1 = (it + 1) * 64;
#pragma unroll
      for (int j = 0; j < 2; ++j) {
        gl16(&kb[(size_t)kv1 * 64 + offk[j]], &kt[nxt][(w * 2 + j) * 512]);
        gl16(&vb[(size_t)kv1 + offv[j]], &vt[nxt][(w * 2 + j) * 512]);
      }
    }
    const bf16* ktc = kt[cur];
    const bf16* vtc = vt[cur];
    // Per 32-kv subtile T: S^T = sum_d K[kv][d] Q[q][d] for both q-subtiles
    // (each kf read feeds 2 MFMAs), then exp/pack/PV before T=1 so sT regs
    // stay short-lived.
#pragma unroll
    for (int T = 0; T < 2; ++T) {
      const bf16* kr = &ktc[(T * 32 + l31) * 64];
      f32x16 sa = {}, sb = {};
#pragma unroll
      for (int ks = 0; ks < 4; ++ks) {
        bf16x8 kf = *(const bf16x8*)&kr[((ks * 2 + hi) ^ swz) * 8];
        sa = MFMA32(kf, qfa[ks], sa);
        sb = MFMA32(kf, qfb[ks], sb);
      }
      // max-free softmax numerator, in-register (q = l31 for every reg)
#pragma unroll
      for (int r = 0; r < 16; ++r) {
        float pa = __builtin_exp2f(sa[r]);
        sa[r] = pa;
        rsa += pa;
        float pb = __builtin_exp2f(sb[r]);
        sb[r] = pb;
        rsb += pb;
      }
      // PV: 2 chunks of 16 kv per T. P A-frag packs straight from regs; its
      // k-slot order (hi=0:{0-3,8-11}, hi=1:{4-7,12-15}) matches permuted vT.
      // Each vf read feeds both q-subtiles' MFMAs.
#pragma unroll
      for (int cc = 0; cc < 2; ++cc) {
        const int c4 = T * 2 + cc, b0 = cc * 8;
        uint4 pua, pub;
        pua.x = pack2(sa[b0 + 0], sa[b0 + 1]);
        pua.y = pack2(sa[b0 + 2], sa[b0 + 3]);
        pua.z = pack2(sa[b0 + 4], sa[b0 + 5]);
        pua.w = pack2(sa[b0 + 6], sa[b0 + 7]);
        pub.x = pack2(sb[b0 + 0], sb[b0 + 1]);
        pub.y = pack2(sb[b0 + 2], sb[b0 + 3]);
        pub.z = pack2(sb[b0 + 4], sb[b0 + 5]);
        pub.w = pack2(sb[b0 + 6], sb[b0 + 7]);
        bf16x8 pfa = __builtin_bit_cast(bf16x8, pua);
        bf16x8 pfb = __builtin_bit_cast(bf16x8, pub);
#pragma unroll
        for (int mf = 0; mf < 2; ++mf) {
          const bf16* vr = &vtc[(mf * 32 + l31) * 64];
          bf16x8 vf = *(const bf16x8*)&vr[((c4 * 2 + hi) ^ swz) * 8];
          oacca[mf] = MFMA32(pfa, vf, oacca[mf]);
          oaccb[mf] = MFMA32(pfb, vf, oaccb[mf]);
        }
      }
    }
    __syncthreads();  // all waves done with cur before it's restaged
  }
  // combine the two hi-half partial row sums (same q = l31)
  rsa += __shfl_xor(rsa, 32);
  rsb += __shfl_xor(rsb, 32);
  float inva = 1.f / rsa, invb = 1.f / rsb;
  const int b = bh >> 3, h = bh & 7;
#pragma unroll
  for (int r = 0; r < 16; ++r) {
    const int ql = (r & 3) + 8 * (r >> 2) + 4 * hi;
    float iqa = __shfl(inva, ql);  // lane ql holds inv for q-row ql
    float iqb = __shfl(invb, ql);
    const int pa = qt0 + w * 64 + ql;
    const size_t ba = ((size_t)(b * 1024 + pa)) * 512 + h * 64;
    const size_t bb = ba + (size_t)32 * 512;  // q-subtile b is +32 rows
#pragma unroll
    for (int mf = 0; mf < 2; ++mf) {
      o[ba + mf * 32 + l31] = (bf16)(oacca[mf][r] * iqa);
      o[bb + mf * 32 + l31] = (bf16)(oaccb[mf][r] * iqb);
    }
  }
}

// ---------------------------------------------------------------------------
extern "C" void kernel_launch(void* const* d_in, const int* in_sizes, int n_in,
                              void* d_out, int out_size, void* d_ws,
                              size_t ws_size, hipStream_t stream) {
  (void)in_sizes;
  (void)n_in;
  (void)out_size;
  (void)ws_size;
  const float* x = (const float*)d_in[0];
  const float* lnw = (const float*)d_in[1];
  const float* lnb = (const float*)d_in[2];
  const float* qkvw = (const float*)d_in[3];
  const float* qkvb = (const float*)d_in[4];
  const float* projw = (const float*)d_in[5];
  const float* projb = (const float*)d_in[6];
  float* out = (float*)d_out;

  const size_t NELEM = 4194304;  // 8192 * 512
  bf16* wc = (bf16*)d_ws;        // qkvw_c [0,786432) projw_c [786432,1048576)
  bf16* xn = wc + 1048576;       // 8 MB; reused as attention output
  bf16* qws = xn + NELEM;        // 8 MB
  bf16* kws = qws + NELEM;       // 8 MB
  bf16* vws = kws + NELEM;       // 8 MB (transposed+col-permuted: b,h,d,p')
  bf16* aws = xn;                // reuse: xn dead after QKV gemm

  prep_kernel<<<dim3(1536), dim3(256), 0, stream>>>(qkvw, projw, wc, x, lnw,
                                                    lnb, xn);
  gemm_qkv<<<dim3(768), dim3(256), 0, stream>>>(xn, wc, qkvb, qws, kws, vws);
  attn_kernel<<<dim3(64, 4), dim3(256), 0, stream>>>(qws, kws, vws, aws);
  gemm_proj<<<dim3(8, 128), dim3(256), 0, stream>>>(wc + 786432, aws, projb, x,
                                                    out);
}

// Round 6
// 157.342 us; speedup vs baseline: 1.0623x; 1.0623x over previous
//
#include <hip/hip_runtime.h>

typedef __bf16 bf16;
typedef __bf16 bf16x8 __attribute__((ext_vector_type(8)));
typedef float f32x4 __attribute__((ext_vector_type(4)));
typedef float f32x16 __attribute__((ext_vector_type(16)));

#define MFMA16(a, b, c) __builtin_amdgcn_mfma_f32_16x16x32_bf16(a, b, c, 0, 0, 0)
#define MFMA32(a, b, c) __builtin_amdgcn_mfma_f32_32x32x16_bf16(a, b, c, 0, 0, 0)

// scale (1/sqrt(64)) * log2(e), folded into q at the QKV epilogue.
#define QSCALE 0.1803368801111137f

static __device__ __forceinline__ unsigned int pack2(float a, float b) {
  unsigned short s0 = __builtin_bit_cast(unsigned short, (bf16)a);
  unsigned short s1 = __builtin_bit_cast(unsigned short, (bf16)b);
  return (unsigned int)s0 | ((unsigned int)s1 << 16);
}

// async global->LDS, 16B per lane. LDS dest is wave-uniform base + lane*16.
static __device__ __forceinline__ void gl16(const bf16* g, bf16* l) {
  __builtin_amdgcn_global_load_lds(
      (const __attribute__((address_space(1))) unsigned int*)g,
      (__attribute__((address_space(3))) unsigned int*)l, 16, 0, 0);
}

// ---------------------------------------------------------------------------
// Fused preprocessing: blocks [0,1024) convert qkv_w/proj_w fp32->bf16;
// blocks [1024,1536) LayerNorm x (B=8,C=512,HW=1024) fp32 -> xn (B*HW,C) bf16.
// ---------------------------------------------------------------------------
__global__ __launch_bounds__(256) void prep_kernel(
    const float* __restrict__ qkvw, const float* __restrict__ projw,
    bf16* __restrict__ wc, const float* __restrict__ x,
    const float* __restrict__ lnw, const float* __restrict__ lnb,
    bf16* __restrict__ xn) {
  __shared__ float tile[512 * 17];  // 34816 B (ln path only)
  __shared__ float wsh[512];
  __shared__ float bsh[512];
  const int t = threadIdx.x;
  if (blockIdx.x < 1024) {
    // ---- weight convert path ----
    int c4 = blockIdx.x * 256 + t;  // 0..262143
    const float* src = (c4 < 196608) ? (qkvw + (size_t)c4 * 4)
                                     : (projw + (size_t)(c4 - 196608) * 4);
    float4 v = *(const float4*)src;
    uint2 o;
    o.x = pack2(v.x, v.y);
    o.y = pack2(v.z, v.w);
    *(uint2*)&wc[(size_t)c4 * 4] = o;
    return;
  }
  // ---- layernorm path ----
  const int bid = blockIdx.x - 1024;
  const int b = bid >> 6;          // 8 batches
  const int p0 = (bid & 63) * 16;  // 64 pixel groups of 16
  for (int i = t; i < 512; i += 256) {
    wsh[i] = lnw[i];
    bsh[i] = lnb[i];
  }
  const float* xb = x + (size_t)b * 524288 + p0;
#pragma unroll
  for (int i = 0; i < 8; ++i) {
    int chunk = t + 256 * i;  // 2048 float4 chunks = 512 rows x 4
    int c = chunk >> 2, px4 = (chunk & 3) * 4;
    float4 v = *(const float4*)&xb[(size_t)c * 1024 + px4];
    tile[c * 17 + px4 + 0] = v.x;
    tile[c * 17 + px4 + 1] = v.y;
    tile[c * 17 + px4 + 2] = v.z;
    tile[c * 17 + px4 + 3] = v.w;
  }
  __syncthreads();
  const int pix = t >> 4, j = t & 15;  // 16 threads per pixel
  float sum = 0.f, sq = 0.f;
#pragma unroll
  for (int i = 0; i < 32; ++i) {
    int c = i * 16 + j;
    float v = tile[c * 17 + pix];
    sum += v;
    sq += v * v;
  }
#pragma unroll
  for (int m = 1; m <= 8; m <<= 1) {
    sum += __shfl_xor(sum, m);
    sq += __shfl_xor(sq, m);
  }
  float mu = sum * (1.f / 512.f);
  float var = sq * (1.f / 512.f) - mu * mu;
  float rstd = rsqrtf(var + 1e-5f);
  unsigned int* orow =
      (unsigned int*)(xn + ((size_t)(b * 1024 + p0 + pix)) * 512);
#pragma unroll
  for (int i = 0; i < 16; ++i) {
    int dw = i * 16 + j;  // dword index 0..255
    int c0 = 2 * dw, c1 = 2 * dw + 1;
    float v0 = (tile[c0 * 17 + pix] - mu) * rstd * wsh[c0] + bsh[c0];
    float v1 = (tile[c1 * 17 + pix] - mu) * rstd * wsh[c1] + bsh[c1];
    orow[dw] = pack2(v0, v1);
  }
}

// ---------------------------------------------------------------------------
// QKV GEMM: C = A * B^T, A=xn (8192x512), B=qkv_w (1536x512). Tile 128x128,
// BK=32, double-buffered global_load_lds staging, one barrier/iter.
// LDS granule swizzle (both-sides-or-neither): chunk (r, g) stores the
// global granule g ^ f(r), f(r) = (r>>1)&3, via pre-swizzled SOURCE address;
// fragment reads fetch slot (quad ^ f(row)).
// Epilogue: +bias, q pre-scaled by QSCALE; q/k scattered (b,h,p,d); V blocks
// transposed through LDS then stored as coalesced 128B vT rows (b,h,d,p).
// vT COLUMN ORDER IS PERMUTED: within each 16-pixel group, p-bit2 and p-bit3
// are swapped (stored order {0-3,8-11,4-7,12-15}). This makes the attention
// PV B-fragment (k = (lane>>5)*8+j of mfma_32x32x16) line up with the
// Sᵀ C-layout (row=(reg&3)+8*(reg>>2)+4*(lane>>5)) with no cross-lane moves.
// ---------------------------------------------------------------------------
__global__ __launch_bounds__(256, 3) void gemm_qkv(
    const bf16* __restrict__ A, const bf16* __restrict__ Bm,
    const float* __restrict__ bias, bf16* __restrict__ oq,
    bf16* __restrict__ okk, bf16* __restrict__ ov) {
  // layout: A buf0 [0,4096), A buf1 [4096,8192), B buf0 [8192,12288),
  // B buf1 [12288,16384). Reused whole as V-transpose scratch in epilogue.
  __shared__ bf16 smem[16384];  // 32KB
  const int t = threadIdx.x;
  const int lane = t & 63, w = t >> 6;
  const int quad = lane >> 4, r16 = lane & 15;
  const int wm = w >> 1, wn = w & 1;
  // panel swizzle: 8 m-tiles x 12 n-tiles per panel
  const int pid = blockIdx.x;
  const int panel = pid / 96, within = pid % 96;
  const int m0 = (panel * 8 + (within & 7)) * 128;
  const int n0 = (within >> 3) * 128;
  // staging: per k-tile each matrix is 512 chunks of 8 elems (128 rows x 4
  // granules); wave w issues j=0,1 for A and for B: chunk c=(w*2+j)*64+lane.
  int sr[2], sc[2];
#pragma unroll
  for (int j = 0; j < 2; ++j) {
    int c = (w * 2 + j) * 64 + lane;
    int r = c >> 2, g = c & 3;
    sr[j] = r;                          // row 0..127
    sc[j] = (g ^ ((r >> 1) & 3)) * 8;   // pre-swizzled source granule
  }
  const int gx = (r16 >> 1) & 3;  // lane-uniform read-side granule xor
  f32x4 acc[4][4] = {};
  // prologue: stage k-tile 0 into buffer 0
#pragma unroll
  for (int j = 0; j < 2; ++j) {
    gl16(&A[(size_t)(m0 + sr[j]) * 512 + sc[j]], &smem[(w * 2 + j) * 512]);
    gl16(&Bm[(size_t)(n0 + sr[j]) * 512 + sc[j]],
         &smem[8192 + (w * 2 + j) * 512]);
  }
  __syncthreads();
  for (int it = 0; it < 16; ++it) {
    const int cur = it & 1, nxt = cur ^ 1;
    if (it < 15) {
      int k1 = (it + 1) * 32;
#pragma unroll
      for (int j = 0; j < 2; ++j) {
        gl16(&A[(size_t)(m0 + sr[j]) * 512 + k1 + sc[j]],
             &smem[nxt * 4096 + (w * 2 + j) * 512]);
        gl16(&Bm[(size_t)(n0 + sr[j]) * 512 + k1 + sc[j]],
             &smem[8192 + nxt * 4096 + (w * 2 + j) * 512]);
      }
    }
    const bf16* ac = &smem[cur * 4096];
    const bf16* bc = &smem[8192 + cur * 4096];
    bf16x8 af[4], bfr[4];
#pragma unroll
    for (int i = 0; i < 4; ++i) {
      int row = wm * 64 + i * 16 + r16;
      af[i] = *(const bf16x8*)&ac[row * 32 + (quad ^ gx) * 8];
    }
#pragma unroll
    for (int i = 0; i < 4; ++i) {
      int row = wn * 64 + i * 16 + r16;
      bfr[i] = *(const bf16x8*)&bc[row * 32 + (quad ^ gx) * 8];
    }
#pragma unroll
    for (int tm = 0; tm < 4; ++tm)
#pragma unroll
      for (int tn = 0; tn < 4; ++tn)
        acc[tm][tn] = MFMA16(af[tm], bfr[tn], acc[tm][tn]);
    __syncthreads();
  }
  if (n0 < 1024) {
    // q / k blocks: direct scatter (d-contiguous 32B segments)
#pragma unroll
    for (int tm = 0; tm < 4; ++tm) {
#pragma unroll
      for (int tn = 0; tn < 4; ++tn) {
        int n = n0 + wn * 64 + tn * 16 + r16;
        float bn = bias[n];
        int comp = n >> 9, h = (n >> 6) & 7, d = n & 63;
#pragma unroll
        for (int r = 0; r < 4; ++r) {
          int m = m0 + wm * 64 + tm * 16 + quad * 4 + r;
          float v = acc[tm][tn][r] + bn;
          int b = m >> 10, p = m & 1023;
          size_t base = ((size_t)(b * 8 + h)) * 65536;
          if (comp == 0)
            oq[base + (size_t)p * 64 + d] = (bf16)(v * QSCALE);
          else
            okk[base + (size_t)p * 64 + d] = (bf16)v;
        }
      }
    }
  } else {
    // V block: per-wave LDS transpose (64d x 64p, stride 64, xor-swizzled at
    // 8-elem granules) then coalesced 128B-row stores of vT (b,h,d,p).
    // Column permutation (p bit2<->bit3 within each 16) baked in here:
    // original p_local = tm*16 + quad*4 + r  ->  stored at
    // tm*16 + swapbits(quad)*4 + r, i.e. granule tm*2+(quad&1), off (quad>>1)*4.
    bf16* tb = &smem[w * 4096];
#pragma unroll
    for (int tn = 0; tn < 4; ++tn) {
      int n = n0 + wn * 64 + tn * 16 + r16;
      float bn = bias[n];
      int row = tn * 16 + r16;  // d_local
#pragma unroll
      for (int tm = 0; tm < 4; ++tm) {
        f32x4 a = acc[tm][tn];
        uint2 pk;
        pk.x = pack2(a[0] + bn, a[1] + bn);
        pk.y = pack2(a[2] + bn, a[3] + bn);
        int g = (tm * 2 + (quad & 1)) ^ (row & 7);
        *(uint2*)&tb[row * 64 + g * 8 + (quad >> 1) * 4] = pk;
      }
    }
    // wave-private region: no barrier needed (lgkmcnt orders write->read)
    const int h = ((n0 - 1024) >> 6) + wn;
    const int mw = m0 + wm * 64;
    const int b = mw >> 10;
    bf16* vbase = ov + ((size_t)(b * 8 + h)) * 65536 + (mw & 1023);
#pragma unroll
    for (int pass = 0; pass < 8; ++pass) {
      int row = pass * 8 + (lane >> 3);
      int g = (lane & 7) ^ (row & 7);
      uint4 vd = *(uint4*)&tb[row * 64 + g * 8];
      *(uint4*)&vbase[(size_t)row * 1024 + (lane & 7) * 8] = vd;
    }
  }
}

// ---------------------------------------------------------------------------
// Proj GEMM: C = W * A^T, W=proj_w (512x512), A=attn out (8192x512).
// Tile 64x64 (grid 8x128 = 1024 blocks), BK=64, double-buffered swizzled
// global_load_lds staging. Epilogue: +bias[m] +residual, fp32 out (B,C,HW).
// ---------------------------------------------------------------------------
__global__ __launch_bounds__(256, 4) void gemm_proj(
    const bf16* __restrict__ Wm, const bf16* __restrict__ A,
    const float* __restrict__ bias, const float* __restrict__ resid,
    float* __restrict__ op) {
  __shared__ bf16 ash[2][64 * 64];
  __shared__ bf16 bsh[2][64 * 64];
  const int t = threadIdx.x;
  const int lane = t & 63, w = t >> 6;
  const int quad = lane >> 4, r16 = lane & 15;
  const int wm = w >> 1, wn = w & 1;
  const int m0 = blockIdx.x * 64, n0 = blockIdx.y * 64;
  int soff[2], sr[2];
#pragma unroll
  for (int j = 0; j < 2; ++j) {
    int c = (w * 2 + j) * 64 + lane;
    int r = c >> 3, cc = c & 7;
    sr[j] = r;
    soff[j] = (cc ^ (r & 7)) * 8;
  }
  f32x4 acc[2][2] = {};
  // prologue: stage k-tile 0 into buffer 0
#pragma unroll
  for (int j = 0; j < 2; ++j) {
    gl16(&Wm[(size_t)(m0 + sr[j]) * 512 + soff[j]], &ash[0][(w * 2 + j) * 512]);
    gl16(&A[(size_t)(n0 + sr[j]) * 512 + soff[j]], &bsh[0][(w * 2 + j) * 512]);
  }
  __syncthreads();
  for (int it = 0; it < 8; ++it) {
    const int cur = it & 1, nxt = cur ^ 1;
    if (it < 7) {
      int k1 = (it + 1) * 64;
#pragma unroll
      for (int j = 0; j < 2; ++j) {
        gl16(&Wm[(size_t)(m0 + sr[j]) * 512 + k1 + soff[j]],
             &ash[nxt][(w * 2 + j) * 512]);
        gl16(&A[(size_t)(n0 + sr[j]) * 512 + k1 + soff[j]],
             &bsh[nxt][(w * 2 + j) * 512]);
      }
    }
#pragma unroll
    for (int kc = 0; kc < 2; ++kc) {
      bf16x8 af[2], bfr[2];
#pragma unroll
      for (int i = 0; i < 2; ++i) {
        int row = wm * 32 + i * 16 + r16;
        af[i] = *(const bf16x8*)&ash[cur][row * 64 +
                                          ((kc * 4 + quad) ^ (r16 & 7)) * 8];
      }
#pragma unroll
      for (int i = 0; i < 2; ++i) {
        int row = wn * 32 + i * 16 + r16;
        bfr[i] = *(const bf16x8*)&bsh[cur][row * 64 +
                                           ((kc * 4 + quad) ^ (r16 & 7)) * 8];
      }
#pragma unroll
      for (int tm = 0; tm < 2; ++tm)
#pragma unroll
        for (int tn = 0; tn < 2; ++tn)
          acc[tm][tn] = MFMA16(af[tm], bfr[tn], acc[tm][tn]);
    }
    __syncthreads();
  }
#pragma unroll
  for (int tm = 0; tm < 2; ++tm) {
#pragma unroll
    for (int tn = 0; tn < 2; ++tn) {
      int n = n0 + wn * 32 + tn * 16 + r16;
      int b = n >> 10, p = n & 1023;
#pragma unroll
      for (int r = 0; r < 4; ++r) {
        int m = m0 + wm * 32 + tm * 16 + quad * 4 + r;
        size_t idx = ((size_t)(b * 512 + m)) * 1024 + p;
        op[idx] = acc[tm][tn][r] + bias[m] + resid[idx];
      }
    }
  }
}

// ---------------------------------------------------------------------------
// Flash attention, 32x32x16-MFMA, 64 q-rows per wave, KV SPLIT ACROSS WAVE
// GROUPS. 512-thread blocks: waves 0-3 (group 0) process kv [0,512), waves
// 4-7 (group 1) kv [512,1024), both over the same 256 q-rows. Max-free
// softmax makes partials additive: O_num and rsum from the two halves are
// summed through a one-shot LDS exchange, then normalized once. This keeps
// R5's 2x read amortization (16 ds_read_b128 feed 32 MFMA32s per wave-iter)
// while doubling resident waves/SIMD vs R5 (2 instead of 1): latency chains
// (4-deep MFMA accum, exp2 runs) now overlap across waves again.
// Grid (64 bh, 4 qt) = 256 blocks = 1 block/CU (8 waves). LDS 64KB: per
// group double-buffered K+V tiles; reused as the fp32 exchange buffer.
// id%8 = bh%8 keeps one bh's K/V on one XCD L2.
// ---------------------------------------------------------------------------
__global__ __launch_bounds__(512, 2) void attn_kernel(
    const bf16* __restrict__ q, const bf16* __restrict__ k,
    const bf16* __restrict__ vT, bf16* __restrict__ o) {
  // [0,16384): K tiles  (g*8192 + buf*4096), [16384,32768): V tiles same.
  __shared__ bf16 smem[32768];     // 64KB
  __shared__ float rsh[2][4][32];  // [a/b][wl][q] partial row sums from g=1
  const int t = threadIdx.x;
  const int lane = t & 63, w = t >> 6;  // 8 waves
  const int g = w >> 2, wl = w & 3;     // kv-half group, q-subtile index
  const int l31 = lane & 31, hi = lane >> 5;
  const int bh = blockIdx.x;
  const int qt0 = blockIdx.y * 256;
  const bf16* qb = q + (size_t)bh * 65536;
  const bf16* kb = k + (size_t)bh * 65536 + (size_t)g * 32768;  // +512 kv rows
  const bf16* vb = vT + (size_t)bh * 65536 + (size_t)g * 512;   // +512 p cols
  // Q as B-fragment: col = q = lane&31, k(=d) = ks*16 + hi*8 + j.
  // Two q-subtiles per wave: rows wl*64+l31 (a) and wl*64+32+l31 (b).
  const int qra = qt0 + wl * 64 + l31;
  bf16x8 qfa[4], qfb[4];
#pragma unroll
  for (int ks = 0; ks < 4; ++ks) {
    qfa[ks] = *(const bf16x8*)&qb[(size_t)qra * 64 + ks * 16 + hi * 8];
    qfb[ks] = *(const bf16x8*)&qb[(size_t)(qra + 32) * 64 + ks * 16 + hi * 8];
  }
  // staging: 512 chunks per 64x64 tile; within its group (4 waves), wave wl
  // issues j=0,1 for K and for V: chunk c=(wl*2+j)*64+lane.
  int offk[2], offv[2];
#pragma unroll
  for (int j = 0; j < 2; ++j) {
    int c = (wl * 2 + j) * 64 + lane;
    int r = c >> 3, cc = c & 7;
    int sw = (cc ^ (r & 7)) * 8;
    offk[j] = r * 64 + sw;    // K: row=kv (stride 64)
    offv[j] = r * 1024 + sw;  // vT: row=d (stride 1024)
  }
  bf16* ktg = smem + g * 8192;          // this group's K double-buffer
  bf16* vtg = smem + 16384 + g * 8192;  // this group's V double-buffer
  f32x16 oacca[2] = {};  // O_a[q=(reg&3)+8*(reg>>2)+4*hi][d=mf*32+l31]
  f32x16 oaccb[2] = {};
  float rsa = 0.f, rsb = 0.f;  // exp row-sum partials (this hi-half's kv)
  const int swz = l31 & 7;
  // prologue: stage tile 0 of this group's half
#pragma unroll
  for (int j = 0; j < 2; ++j) {
    gl16(&kb[offk[j]], &ktg[(wl * 2 + j) * 512]);
    gl16(&vb[offv[j]], &vtg[(wl * 2 + j) * 512]);
  }
  __syncthreads();
  for (int it = 0; it < 8; ++it) {
    const int cur = it & 1, nxt = cur ^ 1;
    if (it < 7) {
      int kv1 = (it + 1) * 64;
#pragma unroll
      for (int j = 0; j < 2; ++j) {
        gl16(&kb[(size_t)kv1 * 64 + offk[j]],
             &ktg[nxt * 4096 + (wl * 2 + j) * 512]);
        gl16(&vb[(size_t)kv1 + offv[j]],
             &vtg[nxt * 4096 + (wl * 2 + j) * 512]);
      }
    }
    const bf16* ktc = &ktg[cur * 4096];
    const bf16* vtc = &vtg[cur * 4096];
    // Per 32-kv subtile T: S^T = mfma(K, Q) for both q-subtiles (each kf
    // read feeds 2 MFMAs), then exp/pack/PV before T=1.
#pragma unroll
    for (int T = 0; T < 2; ++T) {
      const bf16* kr = &ktc[(T * 32 + l31) * 64];
      f32x16 sa = {}, sb = {};
#pragma unroll
      for (int ks = 0; ks < 4; ++ks) {
        bf16x8 kf = *(const bf16x8*)&kr[((ks * 2 + hi) ^ swz) * 8];
        sa = MFMA32(kf, qfa[ks], sa);
        sb = MFMA32(kf, qfb[ks], sb);
      }
      // max-free softmax numerator, in-register (q = l31 for every reg)
#pragma unroll
      for (int r = 0; r < 16; ++r) {
        float pa = __builtin_exp2f(sa[r]);
        sa[r] = pa;
        rsa += pa;
        float pb = __builtin_exp2f(sb[r]);
        sb[r] = pb;
        rsb += pb;
      }
      // PV: 2 chunks of 16 kv per T. P A-frag packs straight from regs; its
      // k-slot order (hi=0:{0-3,8-11}, hi=1:{4-7,12-15}) matches permuted vT.
#pragma unroll
      for (int cc = 0; cc < 2; ++cc) {
        const int c4 = T * 2 + cc, b0 = cc * 8;
        uint4 pua, pub;
        pua.x = pack2(sa[b0 + 0], sa[b0 + 1]);
        pua.y = pack2(sa[b0 + 2], sa[b0 + 3]);
        pua.z = pack2(sa[b0 + 4], sa[b0 + 5]);
        pua.w = pack2(sa[b0 + 6], sa[b0 + 7]);
        pub.x = pack2(sb[b0 + 0], sb[b0 + 1]);
        pub.y = pack2(sb[b0 + 2], sb[b0 + 3]);
        pub.z = pack2(sb[b0 + 4], sb[b0 + 5]);
        pub.w = pack2(sb[b0 + 6], sb[b0 + 7]);
        bf16x8 pfa = __builtin_bit_cast(bf16x8, pua);
        bf16x8 pfb = __builtin_bit_cast(bf16x8, pub);
#pragma unroll
        for (int mf = 0; mf < 2; ++mf) {
          const bf16* vr = &vtc[(mf * 32 + l31) * 64];
          bf16x8 vf = *(const bf16x8*)&vr[((c4 * 2 + hi) ^ swz) * 8];
          oacca[mf] = MFMA32(pfa, vf, oacca[mf]);
          oaccb[mf] = MFMA32(pfb, vf, oaccb[mf]);
        }
      }
    }
    __syncthreads();  // all waves done with cur before it's restaged
  }
  // combine hi-half partial row sums (same q = l31, this kv half)
  rsa += __shfl_xor(rsa, 32);
  rsb += __shfl_xor(rsb, 32);
  // cross-group combine through LDS (K/V tiles are dead; loop-end barrier
  // already separates the last reads from these writes).
  float* cb = (float*)smem;  // 16384 floats = 64KB; wave region wl*4096
  if (g == 1) {
    float* myb = cb + wl * 4096;
#pragma unroll
    for (int mf = 0; mf < 2; ++mf)
#pragma unroll
      for (int r = 0; r < 16; ++r) {
        myb[(mf * 16 + r) * 64 + lane] = oacca[mf][r];       // element-major:
        myb[(32 + mf * 16 + r) * 64 + lane] = oaccb[mf][r];  // conflict-free
      }
    if (hi == 0) {
      rsh[0][wl][l31] = rsa;
      rsh[1][wl][l31] = rsb;
    }
  }
  __syncthreads();
  if (g == 0) {
    const float* pb = cb + wl * 4096;
    float inva = 1.f / (rsa + rsh[0][wl][l31]);
    float invb = 1.f / (rsb + rsh[1][wl][l31]);
    const int b = bh >> 3, h = bh & 7;
#pragma unroll
    for (int r = 0; r < 16; ++r) {
      const int ql = (r & 3) + 8 * (r >> 2) + 4 * hi;
      float iqa = __shfl(inva, ql);  // lane ql holds inv for q-row ql
      float iqb = __shfl(invb, ql);
      const int pa = qt0 + wl * 64 + ql;
      const size_t ba = ((size_t)(b * 1024 + pa)) * 512 + h * 64;
      const size_t bb = ba + (size_t)32 * 512;  // q-subtile b is +32 rows
#pragma unroll
      for (int mf = 0; mf < 2; ++mf) {
        float va = oacca[mf][r] + pb[(mf * 16 + r) * 64 + lane];
        float vb2 = oaccb[mf][r] + pb[(32 + mf * 16 + r) * 64 + lane];
        o[ba + mf * 32 + l31] = (bf16)(va * iqa);
        o[bb + mf * 32 + l31] = (bf16)(vb2 * iqb);
      }
    }
  }
}

// ---------------------------------------------------------------------------
extern "C" void kernel_launch(void* const* d_in, const int* in_sizes, int n_in,
                              void* d_out, int out_size, void* d_ws,
                              size_t ws_size, hipStream_t stream) {
  (void)in_sizes;
  (void)n_in;
  (void)out_size;
  (void)ws_size;
  const float* x = (const float*)d_in[0];
  const float* lnw = (const float*)d_in[1];
  const float* lnb = (const float*)d_in[2];
  const float* qkvw = (const float*)d_in[3];
  const float* qkvb = (const float*)d_in[4];
  const float* projw = (const float*)d_in[5];
  const float* projb = (const float*)d_in[6];
  float* out = (float*)d_out;

  const size_t NELEM = 4194304;  // 8192 * 512
  bf16* wc = (bf16*)d_ws;        // qkvw_c [0,786432) projw_c [786432,1048576)
  bf16* xn = wc + 1048576;       // 8 MB; reused as attention output
  bf16* qws = xn + NELEM;        // 8 MB
  bf16* kws = qws + NELEM;       // 8 MB
  bf16* vws = kws + NELEM;       // 8 MB (transposed+col-permuted: b,h,d,p')
  bf16* aws = xn;                // reuse: xn dead after QKV gemm

  prep_kernel<<<dim3(1536), dim3(256), 0, stream>>>(qkvw, projw, wc, x, lnw,
                                                    lnb, xn);
  gemm_qkv<<<dim3(768), dim3(256), 0, stream>>>(xn, wc, qkvb, qws, kws, vws);
  attn_kernel<<<dim3(64, 4), dim3(512), 0, stream>>>(qws, kws, vws, aws);
  gemm_proj<<<dim3(8, 128), dim3(256), 0, stream>>>(wc + 786432, aws, projb, x,
                                                    out);
}

// Round 7
// 152.859 us; speedup vs baseline: 1.0934x; 1.0293x over previous
//
#include <hip/hip_runtime.h>

typedef __bf16 bf16;
typedef __bf16 bf16x8 __attribute__((ext_vector_type(8)));
typedef float f32x4 __attribute__((ext_vector_type(4)));
typedef float f32x16 __attribute__((ext_vector_type(16)));

#define MFMA16(a, b, c) __builtin_amdgcn_mfma_f32_16x16x32_bf16(a, b, c, 0, 0, 0)
#define MFMA32(a, b, c) __builtin_amdgcn_mfma_f32_32x32x16_bf16(a, b, c, 0, 0, 0)

// scale (1/sqrt(64)) * log2(e), folded into q at the QKV epilogue.
#define QSCALE 0.1803368801111137f

// counted-vmcnt barrier: current tile's loads (4) must have landed; the
// in-flight prefetch (up to 4 more) stays outstanding ACROSS the barrier.
#define WAIT4_BAR()                                    \
  do {                                                 \
    asm volatile("s_waitcnt vmcnt(4)" ::: "memory");   \
    __builtin_amdgcn_sched_barrier(0);                 \
    __builtin_amdgcn_s_barrier();                      \
    __builtin_amdgcn_sched_barrier(0);                 \
  } while (0)
#define WAIT0_BAR()                                    \
  do {                                                 \
    asm volatile("s_waitcnt vmcnt(0)" ::: "memory");   \
    __builtin_amdgcn_sched_barrier(0);                 \
    __builtin_amdgcn_s_barrier();                      \
    __builtin_amdgcn_sched_barrier(0);                 \
  } while (0)

static __device__ __forceinline__ unsigned int pack2(float a, float b) {
  unsigned short s0 = __builtin_bit_cast(unsigned short, (bf16)a);
  unsigned short s1 = __builtin_bit_cast(unsigned short, (bf16)b);
  return (unsigned int)s0 | ((unsigned int)s1 << 16);
}

// async global->LDS, 16B per lane. LDS dest is wave-uniform base + lane*16.
static __device__ __forceinline__ void gl16(const bf16* g, bf16* l) {
  __builtin_amdgcn_global_load_lds(
      (const __attribute__((address_space(1))) unsigned int*)g,
      (__attribute__((address_space(3))) unsigned int*)l, 16, 0, 0);
}

// ---------------------------------------------------------------------------
// Fused preprocessing: blocks [0,1024) convert qkv_w/proj_w fp32->bf16;
// blocks [1024,1536) LayerNorm x (B=8,C=512,HW=1024) fp32 -> xn (B*HW,C) bf16.
// ---------------------------------------------------------------------------
__global__ __launch_bounds__(256) void prep_kernel(
    const float* __restrict__ qkvw, const float* __restrict__ projw,
    bf16* __restrict__ wc, const float* __restrict__ x,
    const float* __restrict__ lnw, const float* __restrict__ lnb,
    bf16* __restrict__ xn) {
  __shared__ float tile[512 * 17];  // 34816 B (ln path only)
  __shared__ float wsh[512];
  __shared__ float bsh[512];
  const int t = threadIdx.x;
  if (blockIdx.x < 1024) {
    // ---- weight convert path ----
    int c4 = blockIdx.x * 256 + t;  // 0..262143
    const float* src = (c4 < 196608) ? (qkvw + (size_t)c4 * 4)
                                     : (projw + (size_t)(c4 - 196608) * 4);
    float4 v = *(const float4*)src;
    uint2 o;
    o.x = pack2(v.x, v.y);
    o.y = pack2(v.z, v.w);
    *(uint2*)&wc[(size_t)c4 * 4] = o;
    return;
  }
  // ---- layernorm path ----
  const int bid = blockIdx.x - 1024;
  const int b = bid >> 6;          // 8 batches
  const int p0 = (bid & 63) * 16;  // 64 pixel groups of 16
  for (int i = t; i < 512; i += 256) {
    wsh[i] = lnw[i];
    bsh[i] = lnb[i];
  }
  const float* xb = x + (size_t)b * 524288 + p0;
#pragma unroll
  for (int i = 0; i < 8; ++i) {
    int chunk = t + 256 * i;  // 2048 float4 chunks = 512 rows x 4
    int c = chunk >> 2, px4 = (chunk & 3) * 4;
    float4 v = *(const float4*)&xb[(size_t)c * 1024 + px4];
    tile[c * 17 + px4 + 0] = v.x;
    tile[c * 17 + px4 + 1] = v.y;
    tile[c * 17 + px4 + 2] = v.z;
    tile[c * 17 + px4 + 3] = v.w;
  }
  __syncthreads();
  const int pix = t >> 4, j = t & 15;  // 16 threads per pixel
  float sum = 0.f, sq = 0.f;
#pragma unroll
  for (int i = 0; i < 32; ++i) {
    int c = i * 16 + j;
    float v = tile[c * 17 + pix];
    sum += v;
    sq += v * v;
  }
#pragma unroll
  for (int m = 1; m <= 8; m <<= 1) {
    sum += __shfl_xor(sum, m);
    sq += __shfl_xor(sq, m);
  }
  float mu = sum * (1.f / 512.f);
  float var = sq * (1.f / 512.f) - mu * mu;
  float rstd = rsqrtf(var + 1e-5f);
  unsigned int* orow =
      (unsigned int*)(xn + ((size_t)(b * 1024 + p0 + pix)) * 512);
#pragma unroll
  for (int i = 0; i < 16; ++i) {
    int dw = i * 16 + j;  // dword index 0..255
    int c0 = 2 * dw, c1 = 2 * dw + 1;
    float v0 = (tile[c0 * 17 + pix] - mu) * rstd * wsh[c0] + bsh[c0];
    float v1 = (tile[c1 * 17 + pix] - mu) * rstd * wsh[c1] + bsh[c1];
    orow[dw] = pack2(v0, v1);
  }
}

// ---------------------------------------------------------------------------
// QKV GEMM: C = A * B^T, A=xn (8192x512), B=qkv_w (1536x512). Tile 128x128,
// BK=32. TRIPLE-BUFFERED counted-vmcnt schedule: prefetch depth 2, one raw
// s_barrier per iter, vmcnt never drained to 0 in steady state (tile it+1's
// loads stay in flight across the barrier). Granule swizzle as before
// (pre-swizzled source, g ^ (r>>1)&3).
// Epilogue: +bias, q pre-scaled by QSCALE; q/k scattered (b,h,p,d); V blocks
// transposed through LDS then stored as coalesced 128B vT rows (b,h,d,p).
// vT COLUMN ORDER IS PERMUTED (p-bit2<->bit3 within each 16) to match the
// attention PV fragment k-slot order.
// ---------------------------------------------------------------------------
__global__ __launch_bounds__(256, 3) void gemm_qkv(
    const bf16* __restrict__ A, const bf16* __restrict__ Bm,
    const float* __restrict__ bias, bf16* __restrict__ oq,
    bf16* __restrict__ okk, bf16* __restrict__ ov) {
  // A bufs at cur*4096, B bufs at 12288 + cur*4096 (cur in 0..2). 48KB.
  // First 16384 elems reused as V-transpose scratch in epilogue.
  __shared__ bf16 smem[24576];
  const int t = threadIdx.x;
  const int lane = t & 63, w = t >> 6;
  const int quad = lane >> 4, r16 = lane & 15;
  const int wm = w >> 1, wn = w & 1;
  // panel swizzle: 8 m-tiles x 12 n-tiles per panel
  const int pid = blockIdx.x;
  const int panel = pid / 96, within = pid % 96;
  const int m0 = (panel * 8 + (within & 7)) * 128;
  const int n0 = (within >> 3) * 128;
  int sr[2], sc[2];
#pragma unroll
  for (int j = 0; j < 2; ++j) {
    int c = (w * 2 + j) * 64 + lane;
    int r = c >> 2, g = c & 3;
    sr[j] = r;                         // row 0..127
    sc[j] = (g ^ ((r >> 1) & 3)) * 8;  // pre-swizzled source granule
  }
  const int gx = (r16 >> 1) & 3;  // lane-uniform read-side granule xor
  f32x4 acc[4][4] = {};
  // prologue: stage k-tiles 0 and 1 into buffers 0 and 1 (8 loads in flight)
#pragma unroll
  for (int pt = 0; pt < 2; ++pt) {
#pragma unroll
    for (int j = 0; j < 2; ++j) {
      gl16(&A[(size_t)(m0 + sr[j]) * 512 + pt * 32 + sc[j]],
           &smem[pt * 4096 + (w * 2 + j) * 512]);
      gl16(&Bm[(size_t)(n0 + sr[j]) * 512 + pt * 32 + sc[j]],
           &smem[12288 + pt * 4096 + (w * 2 + j) * 512]);
    }
  }
  for (int it = 0; it < 16; ++it) {
    const int cur = it % 3;
    if (it < 15) WAIT4_BAR();
    else WAIT0_BAR();
    if (it < 14) {
      const int nb = (it + 2) % 3;
      const int k1 = (it + 2) * 32;
#pragma unroll
      for (int j = 0; j < 2; ++j) {
        gl16(&A[(size_t)(m0 + sr[j]) * 512 + k1 + sc[j]],
             &smem[nb * 4096 + (w * 2 + j) * 512]);
        gl16(&Bm[(size_t)(n0 + sr[j]) * 512 + k1 + sc[j]],
             &smem[12288 + nb * 4096 + (w * 2 + j) * 512]);
      }
    }
    const bf16* ac = &smem[cur * 4096];
    const bf16* bc = &smem[12288 + cur * 4096];
    bf16x8 af[4], bfr[4];
#pragma unroll
    for (int i = 0; i < 4; ++i) {
      int row = wm * 64 + i * 16 + r16;
      af[i] = *(const bf16x8*)&ac[row * 32 + (quad ^ gx) * 8];
    }
#pragma unroll
    for (int i = 0; i < 4; ++i) {
      int row = wn * 64 + i * 16 + r16;
      bfr[i] = *(const bf16x8*)&bc[row * 32 + (quad ^ gx) * 8];
    }
#pragma unroll
    for (int tm = 0; tm < 4; ++tm)
#pragma unroll
      for (int tn = 0; tn < 4; ++tn)
        acc[tm][tn] = MFMA16(af[tm], bfr[tn], acc[tm][tn]);
  }
  __syncthreads();  // all reads of the last buffer done before smem reuse
  if (n0 < 1024) {
    // q / k blocks: direct scatter (d-contiguous 32B segments)
#pragma unroll
    for (int tm = 0; tm < 4; ++tm) {
#pragma unroll
      for (int tn = 0; tn < 4; ++tn) {
        int n = n0 + wn * 64 + tn * 16 + r16;
        float bn = bias[n];
        int comp = n >> 9, h = (n >> 6) & 7, d = n & 63;
#pragma unroll
        for (int r = 0; r < 4; ++r) {
          int m = m0 + wm * 64 + tm * 16 + quad * 4 + r;
          float v = acc[tm][tn][r] + bn;
          int b = m >> 10, p = m & 1023;
          size_t base = ((size_t)(b * 8 + h)) * 65536;
          if (comp == 0)
            oq[base + (size_t)p * 64 + d] = (bf16)(v * QSCALE);
          else
            okk[base + (size_t)p * 64 + d] = (bf16)v;
        }
      }
    }
  } else {
    // V block: per-wave LDS transpose (64d x 64p, stride 64, xor-swizzled at
    // 8-elem granules) then coalesced 128B-row stores of vT (b,h,d,p).
    // p-bit2<->bit3 column permutation baked in (granule tm*2+(quad&1),
    // offset (quad>>1)*4).
    bf16* tb = &smem[w * 4096];
#pragma unroll
    for (int tn = 0; tn < 4; ++tn) {
      int n = n0 + wn * 64 + tn * 16 + r16;
      float bn = bias[n];
      int row = tn * 16 + r16;  // d_local
#pragma unroll
      for (int tm = 0; tm < 4; ++tm) {
        f32x4 a = acc[tm][tn];
        uint2 pk;
        pk.x = pack2(a[0] + bn, a[1] + bn);
        pk.y = pack2(a[2] + bn, a[3] + bn);
        int g = (tm * 2 + (quad & 1)) ^ (row & 7);
        *(uint2*)&tb[row * 64 + g * 8 + (quad >> 1) * 4] = pk;
      }
    }
    // wave-private region: no barrier needed (lgkmcnt orders write->read)
    const int h = ((n0 - 1024) >> 6) + wn;
    const int mw = m0 + wm * 64;
    const int b = mw >> 10;
    bf16* vbase = ov + ((size_t)(b * 8 + h)) * 65536 + (mw & 1023);
#pragma unroll
    for (int pass = 0; pass < 8; ++pass) {
      int row = pass * 8 + (lane >> 3);
      int g = (lane & 7) ^ (row & 7);
      uint4 vd = *(uint4*)&tb[row * 64 + g * 8];
      *(uint4*)&vbase[(size_t)row * 1024 + (lane & 7) * 8] = vd;
    }
  }
}

// ---------------------------------------------------------------------------
// Proj GEMM: C = W * A^T, W=proj_w (512x512), A=attn out (8192x512).
// Tile 64x64 (grid 8x128), BK=64, triple-buffered counted-vmcnt schedule
// (same template as gemm_qkv). Epilogue: +bias[m] +residual, fp32 (B,C,HW).
// ---------------------------------------------------------------------------
__global__ __launch_bounds__(256, 3) void gemm_proj(
    const bf16* __restrict__ Wm, const bf16* __restrict__ A,
    const float* __restrict__ bias, const float* __restrict__ resid,
    float* __restrict__ op) {
  __shared__ bf16 ash[3][64 * 64];
  __shared__ bf16 bsh[3][64 * 64];
  const int t = threadIdx.x;
  const int lane = t & 63, w = t >> 6;
  const int quad = lane >> 4, r16 = lane & 15;
  const int wm = w >> 1, wn = w & 1;
  const int m0 = blockIdx.x * 64, n0 = blockIdx.y * 64;
  int soff[2], sr[2];
#pragma unroll
  for (int j = 0; j < 2; ++j) {
    int c = (w * 2 + j) * 64 + lane;
    int r = c >> 3, cc = c & 7;
    sr[j] = r;
    soff[j] = (cc ^ (r & 7)) * 8;
  }
  f32x4 acc[2][2] = {};
  // prologue: stage k-tiles 0 and 1 (8 loads in flight)
#pragma unroll
  for (int pt = 0; pt < 2; ++pt) {
#pragma unroll
    for (int j = 0; j < 2; ++j) {
      gl16(&Wm[(size_t)(m0 + sr[j]) * 512 + pt * 64 + soff[j]],
           &ash[pt][(w * 2 + j) * 512]);
      gl16(&A[(size_t)(n0 + sr[j]) * 512 + pt * 64 + soff[j]],
           &bsh[pt][(w * 2 + j) * 512]);
    }
  }
  for (int it = 0; it < 8; ++it) {
    const int cur = it % 3;
    if (it < 7) WAIT4_BAR();
    else WAIT0_BAR();
    if (it < 6) {
      const int nb = (it + 2) % 3;
      const int k1 = (it + 2) * 64;
#pragma unroll
      for (int j = 0; j < 2; ++j) {
        gl16(&Wm[(size_t)(m0 + sr[j]) * 512 + k1 + soff[j]],
             &ash[nb][(w * 2 + j) * 512]);
        gl16(&A[(size_t)(n0 + sr[j]) * 512 + k1 + soff[j]],
             &bsh[nb][(w * 2 + j) * 512]);
      }
    }
#pragma unroll
    for (int kc = 0; kc < 2; ++kc) {
      bf16x8 af[2], bfr[2];
#pragma unroll
      for (int i = 0; i < 2; ++i) {
        int row = wm * 32 + i * 16 + r16;
        af[i] = *(const bf16x8*)&ash[cur][row * 64 +
                                          ((kc * 4 + quad) ^ (r16 & 7)) * 8];
      }
#pragma unroll
      for (int i = 0; i < 2; ++i) {
        int row = wn * 32 + i * 16 + r16;
        bfr[i] = *(const bf16x8*)&bsh[cur][row * 64 +
                                           ((kc * 4 + quad) ^ (r16 & 7)) * 8];
      }
#pragma unroll
      for (int tm = 0; tm < 2; ++tm)
#pragma unroll
        for (int tn = 0; tn < 2; ++tn)
          acc[tm][tn] = MFMA16(af[tm], bfr[tn], acc[tm][tn]);
    }
  }
#pragma unroll
  for (int tm = 0; tm < 2; ++tm) {
#pragma unroll
    for (int tn = 0; tn < 2; ++tn) {
      int n = n0 + wn * 32 + tn * 16 + r16;
      int b = n >> 10, p = n & 1023;
#pragma unroll
      for (int r = 0; r < 4; ++r) {
        int m = m0 + wm * 32 + tm * 16 + quad * 4 + r;
        size_t idx = ((size_t)(b * 512 + m)) * 1024 + p;
        op[idx] = acc[tm][tn][r] + bias[m] + resid[idx];
      }
    }
  }
}

// ---------------------------------------------------------------------------
// Flash attention, 32x32x16-MFMA, 32 q-rows/wave (proven R1 geometry:
// 128q/block, 2 blocks/CU) + triple-buffered counted-vmcnt K/V staging.
// Swapped QK^T: S^T = mfma(K, Q) puts q = lane&31; softmax fully in-register.
// Per wave-iter: 16 ds_read_b128 + 16 MFMA32; the next tile's global loads
// stay in flight across the single per-iter s_barrier (no vmcnt(0) drain).
// Grid (64 bh, 8 qt): id%8 = bh%8 keeps one bh's K/V on one XCD L2.
// ---------------------------------------------------------------------------
__global__ __launch_bounds__(256, 2) void attn_kernel(
    const bf16* __restrict__ q, const bf16* __restrict__ k,
    const bf16* __restrict__ vT, bf16* __restrict__ o) {
  __shared__ bf16 kt[3][64 * 64];  // 3x8KB K tiles (kv-row major, swizzled)
  __shared__ bf16 vt[3][64 * 64];  // 3x8KB vT tiles (d-row major, swizzled)
  const int t = threadIdx.x;
  const int lane = t & 63, w = t >> 6;
  const int l31 = lane & 31, hi = lane >> 5;
  const int bh = blockIdx.x;
  const int qt0 = blockIdx.y * 128;
  const bf16* qb = q + (size_t)bh * 65536;
  const bf16* kb = k + (size_t)bh * 65536;
  const bf16* vb = vT + (size_t)bh * 65536;
  // Q as B-fragment: col = q = lane&31, k(=d) = ks*16 + hi*8 + j
  const int qrow = qt0 + w * 32 + l31;
  bf16x8 qf[4];
#pragma unroll
  for (int ks = 0; ks < 4; ++ks)
    qf[ks] = *(const bf16x8*)&qb[(size_t)qrow * 64 + ks * 16 + hi * 8];
  // staging: 512 chunks/tile; wave w issues j=0,1; chunk c=(w*2+j)*64+lane
  int offk[2], offv[2];
#pragma unroll
  for (int j = 0; j < 2; ++j) {
    int c = (w * 2 + j) * 64 + lane;
    int r = c >> 3, cc = c & 7;
    int sw = (cc ^ (r & 7)) * 8;
    offk[j] = r * 64 + sw;    // K: row=kv (stride 64)
    offv[j] = r * 1024 + sw;  // vT: row=d (stride 1024)
  }
  f32x16 oacc[2] = {};  // O[q=(reg&3)+8*(reg>>2)+4*hi][d=mf*32+l31]
  float rsum = 0.f;     // full exp row-sum for q=l31 (this hi-half's kv)
  const int swz = l31 & 7;
  // prologue: stage kv-tiles 0 and 1 into buffers 0 and 1 (8 loads in flight)
#pragma unroll
  for (int pt = 0; pt < 2; ++pt) {
#pragma unroll
    for (int j = 0; j < 2; ++j) {
      gl16(&kb[(size_t)pt * 4096 + offk[j]], &kt[pt][(w * 2 + j) * 512]);
      gl16(&vb[(size_t)pt * 64 + offv[j]], &vt[pt][(w * 2 + j) * 512]);
    }
  }
  for (int it = 0; it < 16; ++it) {
    const int cur = it % 3;
    if (it < 15) WAIT4_BAR();
    else WAIT0_BAR();
    if (it < 14) {
      const int nb = (it + 2) % 3;
      const int kv1 = (it + 2) * 64;
#pragma unroll
      for (int j = 0; j < 2; ++j) {
        gl16(&kb[(size_t)kv1 * 64 + offk[j]], &kt[nb][(w * 2 + j) * 512]);
        gl16(&vb[(size_t)kv1 + offv[j]], &vt[nb][(w * 2 + j) * 512]);
      }
    }
    const bf16* ktc = kt[cur];
    const bf16* vtc = vt[cur];
    // S^T[kv][q] = sum_d K[kv][d] Q[q][d]: two 32-kv tiles, 4 k-steps each.
    f32x16 sT[2] = {};
#pragma unroll
    for (int T = 0; T < 2; ++T) {
      const bf16* kr = &ktc[(T * 32 + l31) * 64];
#pragma unroll
      for (int ks = 0; ks < 4; ++ks) {
        bf16x8 kf = *(const bf16x8*)&kr[((ks * 2 + hi) ^ swz) * 8];
        sT[T] = MFMA32(kf, qf[ks], sT[T]);
      }
    }
    // max-free softmax numerator, all in-register (q = l31 for every reg)
#pragma unroll
    for (int T = 0; T < 2; ++T)
#pragma unroll
      for (int r = 0; r < 16; ++r) {
        float p = __builtin_exp2f(sT[T][r]);
        sT[T][r] = p;
        rsum += p;
      }
    // PV: 4 chunks of 16 kv. P A-frag packs straight from regs; its k-slot
    // order (hi=0:{0-3,8-11}, hi=1:{4-7,12-15}) matches the permuted vT.
#pragma unroll
    for (int c4 = 0; c4 < 4; ++c4) {
      const int T = c4 >> 1, b0 = (c4 & 1) * 8;
      uint4 pui;
      pui.x = pack2(sT[T][b0 + 0], sT[T][b0 + 1]);
      pui.y = pack2(sT[T][b0 + 2], sT[T][b0 + 3]);
      pui.z = pack2(sT[T][b0 + 4], sT[T][b0 + 5]);
      pui.w = pack2(sT[T][b0 + 6], sT[T][b0 + 7]);
      bf16x8 pf = __builtin_bit_cast(bf16x8, pui);
#pragma unroll
      for (int mf = 0; mf < 2; ++mf) {
        const bf16* vr = &vtc[(mf * 32 + l31) * 64];
        bf16x8 vf = *(const bf16x8*)&vr[((c4 * 2 + hi) ^ swz) * 8];
        oacc[mf] = MFMA32(pf, vf, oacc[mf]);
      }
    }
  }
  // combine the two hi-half partial row sums (same q = l31)
  rsum += __shfl_xor(rsum, 32);
  float inv = 1.f / rsum;
  const int b = bh >> 3, h = bh & 7;
#pragma unroll
  for (int r = 0; r < 16; ++r) {
    const int ql = (r & 3) + 8 * (r >> 2) + 4 * hi;
    float invq = __shfl(inv, ql);  // lane ql holds inv for q-row ql
    const int p = qt0 + w * 32 + ql;
    const size_t base = ((size_t)(b * 1024 + p)) * 512 + h * 64;
#pragma unroll
    for (int mf = 0; mf < 2; ++mf)
      o[base + mf * 32 + l31] = (bf16)(oacc[mf][r] * invq);
  }
}

// ---------------------------------------------------------------------------
extern "C" void kernel_launch(void* const* d_in, const int* in_sizes, int n_in,
                              void* d_out, int out_size, void* d_ws,
                              size_t ws_size, hipStream_t stream) {
  (void)in_sizes;
  (void)n_in;
  (void)out_size;
  (void)ws_size;
  const float* x = (const float*)d_in[0];
  const float* lnw = (const float*)d_in[1];
  const float* lnb = (const float*)d_in[2];
  const float* qkvw = (const float*)d_in[3];
  const float* qkvb = (const float*)d_in[4];
  const float* projw = (const float*)d_in[5];
  const float* projb = (const float*)d_in[6];
  float* out = (float*)d_out;

  const size_t NELEM = 4194304;  // 8192 * 512
  bf16* wc = (bf16*)d_ws;        // qkvw_c [0,786432) projw_c [786432,1048576)
  bf16* xn = wc + 1048576;       // 8 MB; reused as attention output
  bf16* qws = xn + NELEM;        // 8 MB
  bf16* kws = qws + NELEM;       // 8 MB
  bf16* vws = kws + NELEM;       // 8 MB (transposed+col-permuted: b,h,d,p')
  bf16* aws = xn;                // reuse: xn dead after QKV gemm

  prep_kernel<<<dim3(1536), dim3(256), 0, stream>>>(qkvw, projw, wc, x, lnw,
                                                    lnb, xn);
  gemm_qkv<<<dim3(768), dim3(256), 0, stream>>>(xn, wc, qkvb, qws, kws, vws);
  attn_kernel<<<dim3(64, 8), dim3(256), 0, stream>>>(qws, kws, vws, aws);
  gemm_proj<<<dim3(8, 128), dim3(256), 0, stream>>>(wc + 786432, aws, projb, x,
                                                    out);
}